// Round 1
// 1331.332 us; speedup vs baseline: 1.3804x; 1.3804x over previous
//
#include <hip/hip_runtime.h>

// scatter_mean over a SORTED residue index.
//   atom_features: [N=2,000,000, D=128] fp32
//   residue_index: [N] int32 (sorted ascending, values in [0, R))
//   out:           [R=250,000, D=128] fp32  = segment_sum / max(count,1)
//
// v2: the previous kernel was latency-bound (hbm 10%, VALU 20%, occ 88%):
// 250K waves x 2 binary searches = 10.5M serially-dependent random loads
// into an 8MB index (doesn't fit one XCD's 4MB L2 -> ~400-900cy/step).
// Replace with a CSR row_start[R+1] built in one O(N) pass (kernel 1);
// pooling (kernel 2) then needs only two L2-hit bound lookups per wave
// and becomes feature-streaming-bound.

// ---------------- kernel 1: build row_start ----------------
// row_start[r] = first atom index with ridx >= r; row_start[R] = N.
// Boundary atom i (ridx[i] != ridx[i-1]) writes start=i for every residue
// in (ridx[i-1], ridx[i]] (forward-fills empty residues; ~0.03% empties).
__global__ __launch_bounds__(256) void build_row_start_kernel(
        const int* __restrict__ ridx,
        int* __restrict__ row_start,
        int n_atoms, int n_res) {
    const int stride = gridDim.x * blockDim.x;
    for (int i = blockIdx.x * blockDim.x + threadIdx.x; i < n_atoms; i += stride) {
        const int cur  = ridx[i];
        const int prev = (i == 0) ? -1 : ridx[i - 1];
        // most atoms: prev == cur -> no iterations
        for (int v = prev + 1; v <= cur; ++v) row_start[v] = i;
        if (i == n_atoms - 1) {
            for (int v = cur + 1; v <= n_res; ++v) row_start[v] = n_atoms;
        }
    }
}

// ---------------- kernel 2: pool ----------------
// One wave per residue; lane owns 2 columns (float2) -> a 128-float row is
// one coalesced 512B wave access. Rows of one residue are contiguous
// (sorted index) so feature reads stream linearly through HBM.
__global__ __launch_bounds__(256) void pool_kernel(
        const float* __restrict__ feat,    // [N,128]
        const int* __restrict__ row_start, // [R+1]
        float* __restrict__ out,           // [R,128]
        int n_res) {
    const int gtid = blockIdx.x * blockDim.x + threadIdx.x;
    const int wave = gtid >> 6;
    const int lane = threadIdx.x & 63;
    if (wave >= n_res) return;

    const int r = wave;
    // 1MB array, read-shared by adjacent waves -> L2-hit; same address across
    // lanes -> hardware broadcast.
    const int start = row_start[r];
    const int end   = row_start[r + 1];

    const float2* __restrict__ f2 = (const float2*)feat;  // row stride 64
    float2 acc = make_float2(0.f, 0.f);
    for (int i = start; i < end; ++i) {
        float2 v = f2[(size_t)i * 64 + lane];
        acc.x += v.x;
        acc.y += v.y;
    }

    const int cnt = end - start;
    const float scale = 1.0f / (float)(cnt > 0 ? cnt : 1);
    float2* o2 = (float2*)out;
    o2[(size_t)r * 64 + lane] = make_float2(acc.x * scale, acc.y * scale);
}

// ---------------- fallback (previous kernel) if workspace too small ----------
__device__ __forceinline__ int lower_bound(const int* __restrict__ idx,
                                           int n, int val) {
    int lo = 0, hi = n;
    while (lo < hi) {
        int mid = (lo + hi) >> 1;
        if (idx[mid] < val) lo = mid + 1;
        else hi = mid;
    }
    return lo;
}

__global__ __launch_bounds__(256) void residue_pool_search_kernel(
        const float* __restrict__ feat,
        const int* __restrict__ ridx,
        float* __restrict__ out,
        int n_atoms, int n_res) {
    const int gtid = blockIdx.x * blockDim.x + threadIdx.x;
    const int wave = gtid >> 6;
    const int lane = threadIdx.x & 63;
    if (wave >= n_res) return;

    const int r = wave;
    const int start = lower_bound(ridx, n_atoms, r);
    const int end   = lower_bound(ridx, n_atoms, r + 1);

    const float2* __restrict__ f2 = (const float2*)feat;
    float2 acc = make_float2(0.f, 0.f);
    for (int i = start; i < end; ++i) {
        float2 v = f2[(size_t)i * 64 + lane];
        acc.x += v.x;
        acc.y += v.y;
    }

    const int cnt = end - start;
    const float scale = 1.0f / (float)(cnt > 0 ? cnt : 1);
    float2* o2 = (float2*)out;
    o2[(size_t)r * 64 + lane] = make_float2(acc.x * scale, acc.y * scale);
}

extern "C" void kernel_launch(void* const* d_in, const int* in_sizes, int n_in,
                              void* d_out, int out_size, void* d_ws, size_t ws_size,
                              hipStream_t stream) {
    const float* feat = (const float*)d_in[0];
    const int*   ridx = (const int*)d_in[1];
    float* out = (float*)d_out;

    const int n_atoms = in_sizes[1];          // 2,000,000
    const int n_res   = out_size / 128;       // 250,000

    const size_t row_start_bytes = (size_t)(n_res + 1) * sizeof(int);

    if (d_ws != nullptr && ws_size >= row_start_bytes) {
        int* row_start = (int*)d_ws;

        // kernel 1: O(N) boundary scatter, grid-stride, ~2048 blocks
        {
            const int threads = 256;
            int blocks = (n_atoms + threads - 1) / threads;
            if (blocks > 2048) blocks = 2048;
            build_row_start_kernel<<<blocks, threads, 0, stream>>>(
                ridx, row_start, n_atoms, n_res);
        }

        // kernel 2: one wave per residue
        {
            const int threads = 256;
            const long long total_threads = (long long)n_res * 64;
            const int blocks = (int)((total_threads + threads - 1) / threads);
            pool_kernel<<<blocks, threads, 0, stream>>>(
                feat, row_start, out, n_res);
        }
    } else {
        // fallback: previous (verified) binary-search version
        const int threads = 256;
        const long long total_threads = (long long)n_res * 64;
        const int blocks = (int)((total_threads + threads - 1) / threads);
        residue_pool_search_kernel<<<blocks, threads, 0, stream>>>(
            feat, ridx, out, n_atoms, n_res);
    }
}